// Round 3
// baseline (5453.174 us; speedup 1.0000x reference)
//
#include <hip/hip_runtime.h>
#include <math.h>

// Fully-fused CapsuleNet forward, v2.
// 256 blocks x 8 waves. Block owns E=4 batch elements; waves split the
// input-capsule axis i (8-way). Each W register load feeds 4 elements'
// FMAs (4x L2 traffic cut vs v1). Logit state vs = sum of squash outputs
// (affine-logit identity) lives in LDS, lane-major [j*64+l] (conflict-free).
// Per routing pass, cross-wave partial s reduced via LDS, squash on one wave.

#define WAVES 8
#define EPB 4

template<int I, int Di, int O, int Do, bool FINAL>
__device__ __forceinline__ void layer(const float* __restrict__ W,
                                      float (* __restrict__ h)[1024],
                                      float (* __restrict__ vsl)[1024],
                                      float (* __restrict__ red)[1024],
                                      float* __restrict__ out,
                                      int e0, int w, int l) {
    constexpr int LPO = Do / 16;
    constexpr int ACT = O * LPO;
    static_assert(ACT <= 64, "lane mapping");
    const int o   = l / LPO;
    const int d0  = (l % LPO) * 16;
    const bool act = l < ACT;
    const int oa  = act ? o : 0;           // clamped for safe addressing
    const int da  = act ? d0 : 0;

    for (int r = 0; r < 3; ++r) {
        float sacc[EPB][16];
        #pragma unroll
        for (int e = 0; e < EPB; ++e)
            #pragma unroll
            for (int j = 0; j < 16; ++j) sacc[e][j] = 0.f;

        for (int i = w; i < I; i += WAVES) {
            float xh[EPB][16];
            #pragma unroll
            for (int e = 0; e < EPB; ++e)
                #pragma unroll
                for (int j = 0; j < 16; ++j) xh[e][j] = 0.f;

            const float* wr = W + (((size_t)oa * I + i) * Do + da) * Di;
            #pragma unroll
            for (int c0 = 0; c0 < Di; c0 += 8) {
                float hreg[EPB][8];
                #pragma unroll
                for (int e = 0; e < EPB; ++e)
                    #pragma unroll
                    for (int c = 0; c < 8; ++c)
                        hreg[e][c] = h[e][i * Di + c0 + c];   // LDS broadcast
                #pragma unroll
                for (int j = 0; j < 16; ++j) {
                    float4 wa = *(const float4*)(wr + j * Di + c0);
                    float4 wb = *(const float4*)(wr + j * Di + c0 + 4);
                    float wv[8] = {wa.x, wa.y, wa.z, wa.w, wb.x, wb.y, wb.z, wb.w};
                    #pragma unroll
                    for (int e = 0; e < EPB; ++e)
                        #pragma unroll
                        for (int c = 0; c < 8; ++c)
                            xh[e][j] += wv[c] * hreg[e][c];
                }
            }

            #pragma unroll
            for (int e = 0; e < EPB; ++e) {
                float cc;
                if (r == 0) {
                    cc = 1.0f;                       // uniform c; 1/O folded at reduce
                } else {
                    float lp = 0.f;
                    #pragma unroll
                    for (int j = 0; j < 16; ++j) lp += vsl[e][j * 64 + l] * xh[e][j];
                    if constexpr (LPO >= 2) lp += __shfl_xor(lp, 1, 64);
                    if constexpr (LPO >= 4) lp += __shfl_xor(lp, 2, 64);
                    float ev = act ? __expf(lp) : 0.f;
                    float tot = ev;                   // counts each o LPO times
                    tot += __shfl_xor(tot, 1, 64);
                    tot += __shfl_xor(tot, 2, 64);
                    tot += __shfl_xor(tot, 4, 64);
                    tot += __shfl_xor(tot, 8, 64);
                    tot += __shfl_xor(tot, 16, 64);
                    tot += __shfl_xor(tot, 32, 64);
                    cc = ev * (float)LPO / tot;
                }
                #pragma unroll
                for (int j = 0; j < 16; ++j) sacc[e][j] += cc * xh[e][j];
            }
        }

        // cross-wave reduction + squash, one element at a time
        #pragma unroll
        for (int e = 0; e < EPB; ++e) {
            #pragma unroll
            for (int j = 0; j < 16; ++j) red[w][j * 64 + l] = sacc[e][j];
            __syncthreads();
            if (w == e) {
                float s[16];
                #pragma unroll
                for (int j = 0; j < 16; ++j) {
                    float t = 0.f;
                    #pragma unroll
                    for (int ww = 0; ww < WAVES; ++ww) t += red[ww][j * 64 + l];
                    if (r == 0) t *= (1.0f / O);
                    s[j] = t;
                }
                float n2 = 0.f;
                #pragma unroll
                for (int j = 0; j < 16; ++j) n2 += s[j] * s[j];
                if constexpr (LPO >= 2) n2 += __shfl_xor(n2, 1, 64);
                if constexpr (LPO >= 4) n2 += __shfl_xor(n2, 2, 64);
                float nrm   = sqrtf(n2);
                float scale = n2 / ((1.f + n2) * (nrm + 1e-8f));

                if (r < 2) {
                    if (act) {
                        #pragma unroll
                        for (int j = 0; j < 16; ++j) {
                            float prev = (r == 0) ? 0.f : vsl[e][j * 64 + l];
                            vsl[e][j * 64 + l] = prev + scale * s[j];
                        }
                    }
                } else if constexpr (FINAL) {
                    float q = 0.f;
                    #pragma unroll
                    for (int j = 0; j < 16; ++j) { float vj = scale * s[j]; q += vj * vj; }
                    if constexpr (LPO >= 2) q += __shfl_xor(q, 1, 64);
                    if constexpr (LPO >= 4) q += __shfl_xor(q, 2, 64);
                    if (act && (l % LPO) == 0) out[(size_t)(e0 + e) * O + o] = sqrtf(q);
                } else {
                    if (act) {
                        #pragma unroll
                        for (int j = 0; j < 16; ++j) h[e][o * Do + d0 + j] = scale * s[j];
                    }
                }
            }
            __syncthreads();
        }
    }
}

__global__ __launch_bounds__(512) void caps_fused(const float* __restrict__ x,
                                                  const float* __restrict__ W0,
                                                  const float* __restrict__ W1,
                                                  const float* __restrict__ W2,
                                                  float* __restrict__ out) {
    __shared__ float h[EPB][1024];
    __shared__ float vsl[EPB][1024];
    __shared__ float red[WAVES][1024];

    const int w  = threadIdx.x >> 6;
    const int l  = threadIdx.x & 63;
    const int e0 = blockIdx.x * EPB;

    // load 4 x-rows (4096 floats) coalesced
    const float4* xr = (const float4*)(x + (size_t)e0 * 1024);
    for (int k = threadIdx.x; k < EPB * 256; k += 512) {
        int e = k >> 8, pos = k & 255;
        ((float4*)h[e])[pos] = xr[(size_t)e * 256 + pos];
    }
    __syncthreads();

    layer<128,  8, 64, 16, false>(W0, h, vsl, red, out, e0, w, l);
    layer< 64, 16, 32, 32, false>(W1, h, vsl, red, out, e0, w, l);
    layer< 32, 32, 10, 64, true >(W2, h, vsl, red, out, e0, w, l);
}

extern "C" void kernel_launch(void* const* d_in, const int* in_sizes, int n_in,
                              void* d_out, int out_size, void* d_ws, size_t ws_size,
                              hipStream_t stream) {
    const float* x  = (const float*)d_in[0];   // [1024,1024]
    const float* W0 = (const float*)d_in[1];   // [64,128,16,8]
    const float* W1 = (const float*)d_in[2];   // [32,64,32,16]
    const float* W2 = (const float*)d_in[3];   // [10,32,64,32]
    float* out = (float*)d_out;                // [1024,10]

    caps_fused<<<256, 512, 0, stream>>>(x, W0, W1, W2, out);
}

// Round 4
// 2923.201 us; speedup vs baseline: 1.8655x; 1.8655x over previous
//
#include <hip/hip_runtime.h>
#include <math.h>

// CapsuleNet forward, v3: i-split multi-kernel.
//  k_contract<I,Di,O,Do,SI,CI,NBUF,LOGIT>: grid (SE=32, SI=8), 512 thr.
//    Block stages W[:, i-slice, :, :] into LDS (transposed [dc][o], dbuf where
//    it fits), computes partial s for its 32 elements over its I/SI i's.
//    LOGIT passes compute per-i logits from vs (packed bf16 in regs), softmax
//    over o via wave butterflies (i-local!), weighted-accumulate.
//  k_squash<O,Do,SI,MODE>: reduce SI partials, squash; MODE 0: vs=v,
//    1: vs+=v, 2: h_next=v, 3: out=||v||.
// vs carry = affine-logit identity (b_r = (sum v_j).x_hat).

#define CE 32  // elements per contract block (8 waves x 4)

template<int I,int Di,int O,int Do,int SI,int CI,int NBUF,bool LOGIT>
__global__ __launch_bounds__(512,2) void k_contract(
    const float* __restrict__ W, const float* __restrict__ hsrc,
    const float* __restrict__ vsbuf, float* __restrict__ ps)
{
    constexpr int DoDi = Do*Di;
    constexpr int LPO  = Do/16;
    constexpr int ACT  = O*LPO;
    constexpr int IR   = I/SI;
    constexpr int NCH  = IR/CI;
    constexpr int SLAB = CI*DoDi*O;
    __shared__ float wsl[NBUF*SLAB];

    const int tid = threadIdx.x;
    const int w   = tid>>6, l = tid&63;
    const int se  = blockIdx.x, si = blockIdx.y;
    const int i0  = si*IR;
    const int o   = l/LPO;
    const int d0  = (l%LPO)*16;
    const bool act = l < ACT;
    const int oa  = act ? o : 0, da = act ? d0 : 0;

    int e[4];
    #pragma unroll
    for (int k=0;k<4;++k) e[k] = se*CE + w + 8*k;

    // vs for logit passes, packed bf16 pairs (reg saver; outputs ~1e-28, tol-free)
    unsigned vp[4][8];
    if constexpr (LOGIT) {
        #pragma unroll
        for (int k=0;k<4;++k)
            #pragma unroll
            for (int jj=0;jj<8;++jj) {
                float2 f2 = *(const float2*)(vsbuf + (size_t)e[k]*1024 + oa*Do + da + 2*jj);
                vp[k][jj] = (__float_as_uint(f2.y)&0xffff0000u) | (__float_as_uint(f2.x)>>16);
            }
    }

    float sacc[4][16];
    #pragma unroll
    for (int k=0;k<4;++k)
        #pragma unroll
        for (int j=0;j<16;++j) sacc[k][j]=0.f;

    auto stage = [&](int ch, int buf){
        constexpr int NF4 = SLAB/4;
        const int ib = i0 + ch*CI;
        for (int idx = tid; idx < NF4; idx += 512) {
            int o2   = idx % O;
            int rest = idx / O;
            int ci   = rest / (DoDi/4);
            int q    = rest % (DoDi/4);
            float4 f = *(const float4*)(W + ((size_t)o2*I + ib + ci)*DoDi + 4*q);
            float* dstp = wsl + buf*SLAB + ci*(DoDi*O);
            dstp[(4*q+0)*O + o2] = f.x;
            dstp[(4*q+1)*O + o2] = f.y;
            dstp[(4*q+2)*O + o2] = f.z;
            dstp[(4*q+3)*O + o2] = f.w;
        }
    };

    auto compute = [&](int ch, int buf){
        #pragma unroll
        for (int ci=0; ci<CI; ++ci) {
            const int i = i0 + ch*CI + ci;
            const float* wb = wsl + buf*SLAB + ci*(DoDi*O);
            float xh[4][16];
            #pragma unroll
            for (int k=0;k<4;++k)
                #pragma unroll
                for (int j=0;j<16;++j) xh[k][j]=0.f;

            #pragma unroll
            for (int c0=0; c0<Di; c0+=4) {
                float hreg[4][4];
                #pragma unroll
                for (int k=0;k<4;++k) {
                    float4 t = *(const float4*)(hsrc + (size_t)e[k]*(I*Di) + i*Di + c0);
                    hreg[k][0]=t.x; hreg[k][1]=t.y; hreg[k][2]=t.z; hreg[k][3]=t.w;
                }
                #pragma unroll
                for (int j=0;j<16;++j) {
                    #pragma unroll
                    for (int c=0;c<4;++c) {
                        float wv = wb[((da+j)*Di + c0+c)*O + oa];
                        #pragma unroll
                        for (int k=0;k<4;++k) xh[k][j] += wv*hreg[k][c];
                    }
                }
            }

            if constexpr (LOGIT) {
                float cc[4];
                #pragma unroll
                for (int k=0;k<4;++k) {
                    float lp=0.f;
                    #pragma unroll
                    for (int jj=0;jj<8;++jj) {
                        float lo = __uint_as_float(vp[k][jj]<<16);
                        float hi = __uint_as_float(vp[k][jj]&0xffff0000u);
                        lp += lo*xh[k][2*jj] + hi*xh[k][2*jj+1];
                    }
                    if constexpr (LPO>=2) lp += __shfl_xor(lp,1,64);
                    if constexpr (LPO>=4) lp += __shfl_xor(lp,2,64);
                    float ev = act ? __expf(lp) : 0.f;
                    float tot = ev;
                    tot += __shfl_xor(tot,1,64);  tot += __shfl_xor(tot,2,64);
                    tot += __shfl_xor(tot,4,64);  tot += __shfl_xor(tot,8,64);
                    tot += __shfl_xor(tot,16,64); tot += __shfl_xor(tot,32,64);
                    cc[k] = ev*(float)LPO/tot;    // butterfly counts each o LPO times
                }
                #pragma unroll
                for (int k=0;k<4;++k)
                    #pragma unroll
                    for (int j=0;j<16;++j) sacc[k][j] += cc[k]*xh[k][j];
            } else {
                #pragma unroll
                for (int k=0;k<4;++k)
                    #pragma unroll
                    for (int j=0;j<16;++j) sacc[k][j] += xh[k][j];
            }
        }
    };

    stage(0,0);
    __syncthreads();
    for (int ch=0; ch<NCH; ++ch) {
        if constexpr (NBUF==2) {
            int buf = ch&1;
            if (ch+1<NCH) stage(ch+1, buf^1);
            compute(ch, buf);
            __syncthreads();
        } else {
            compute(ch, 0);
            __syncthreads();
            if (ch+1<NCH) { stage(ch+1, 0); __syncthreads(); }
        }
    }

    if (act) {
        #pragma unroll
        for (int k=0;k<4;++k) {
            float* pp = ps + ((size_t)e[k]*SI + si)*1024 + oa*Do + da;
            #pragma unroll
            for (int q=0;q<4;++q) {
                float4 f; f.x=sacc[k][4*q]; f.y=sacc[k][4*q+1]; f.z=sacc[k][4*q+2]; f.w=sacc[k][4*q+3];
                *(float4*)(pp + 4*q) = f;
            }
        }
    }
}

template<int O,int Do,int SI,int MODE>
__global__ __launch_bounds__(256) void k_squash(
    const float* __restrict__ ps, float* __restrict__ vsbuf, float* __restrict__ dst)
{
    constexpr int LPO=Do/16, ACT=O*LPO;
    const int tid=threadIdx.x, w=tid>>6, l=tid&63;
    const int e = blockIdx.x*4 + w;
    const int o=l/LPO, d0=(l%LPO)*16;
    const bool act = l < ACT;
    const int oa=act?o:0, da=act?d0:0;

    float s[16];
    #pragma unroll
    for (int j=0;j<16;++j) s[j]=0.f;
    if (act) {
        for (int si=0; si<SI; ++si) {
            const float* p = ps + ((size_t)e*SI + si)*1024 + oa*Do + da;
            #pragma unroll
            for (int q=0;q<4;++q) {
                float4 f = *(const float4*)(p + 4*q);
                s[4*q]+=f.x; s[4*q+1]+=f.y; s[4*q+2]+=f.z; s[4*q+3]+=f.w;
            }
        }
    }
    if constexpr (MODE==0) {
        #pragma unroll
        for (int j=0;j<16;++j) s[j] *= (1.0f/O);
    }
    float n2=0.f;
    #pragma unroll
    for (int j=0;j<16;++j) n2 += s[j]*s[j];
    if constexpr (LPO>=2) n2 += __shfl_xor(n2,1,64);
    if constexpr (LPO>=4) n2 += __shfl_xor(n2,2,64);
    float nrm   = sqrtf(n2);
    float scale = n2/((1.f+n2)*(nrm+1e-8f));

    if constexpr (MODE==0) {
        if (act) {
            float* vp = vsbuf + (size_t)e*1024 + oa*Do + da;
            #pragma unroll
            for (int q=0;q<4;++q) {
                float4 f; f.x=scale*s[4*q]; f.y=scale*s[4*q+1]; f.z=scale*s[4*q+2]; f.w=scale*s[4*q+3];
                *(float4*)(vp+4*q) = f;
            }
        }
    } else if constexpr (MODE==1) {
        if (act) {
            float* vp = vsbuf + (size_t)e*1024 + oa*Do + da;
            #pragma unroll
            for (int q=0;q<4;++q) {
                float4 old = *(const float4*)(vp+4*q);
                float4 f; f.x=old.x+scale*s[4*q]; f.y=old.y+scale*s[4*q+1];
                f.z=old.z+scale*s[4*q+2]; f.w=old.w+scale*s[4*q+3];
                *(float4*)(vp+4*q) = f;
            }
        }
    } else if constexpr (MODE==2) {
        if (act) {
            float* hp = dst + (size_t)e*1024 + oa*Do + da;
            #pragma unroll
            for (int q=0;q<4;++q) {
                float4 f; f.x=scale*s[4*q]; f.y=scale*s[4*q+1]; f.z=scale*s[4*q+2]; f.w=scale*s[4*q+3];
                *(float4*)(hp+4*q) = f;
            }
        }
    } else {
        float qq=0.f;
        #pragma unroll
        for (int j=0;j<16;++j) { float vj=scale*s[j]; qq += vj*vj; }
        if constexpr (LPO>=2) qq += __shfl_xor(qq,1,64);
        if constexpr (LPO>=4) qq += __shfl_xor(qq,2,64);
        if (act && (l%LPO)==0) dst[(size_t)e*O + o] = sqrtf(qq);
    }
}

// ---------------- fallback (round-1 kernel, known-pass) for small ws ----------------
template<int I, int Di, int O, int Do, bool FINAL>
__device__ __forceinline__ void fb_layer(const float* __restrict__ W, float* __restrict__ hl,
                                         float* __restrict__ out, int e, int l) {
    constexpr int LPO = Do / 16;
    constexpr int ACT = O * LPO;
    const int o  = l / LPO;
    const int d0 = (l % LPO) * 16;
    const bool act = (l < ACT);
    float vs[16];
    #pragma unroll
    for (int j = 0; j < 16; ++j) vs[j] = 0.f;
    for (int r = 0; r < 3; ++r) {
        float sacc[16];
        #pragma unroll
        for (int j = 0; j < 16; ++j) sacc[j] = 0.f;
        for (int i = 0; i < I; ++i) {
            if ((i & 15) == 0) __syncthreads();
            float xh[16];
            #pragma unroll
            for (int j = 0; j < 16; ++j) xh[j] = 0.f;
            if (act) {
                const float* wb = W + ((size_t)(o * I + i) * Do + d0) * Di;
                #pragma unroll
                for (int j = 0; j < 16; ++j) {
                    const float4* wr = (const float4*)(wb + j * Di);
                    float acc = 0.f;
                    #pragma unroll
                    for (int c4 = 0; c4 < Di / 4; ++c4) {
                        float4 wv = wr[c4];
                        float4 hv = *(const float4*)(hl + i * Di + c4 * 4);
                        acc += wv.x*hv.x + wv.y*hv.y + wv.z*hv.z + wv.w*hv.w;
                    }
                    xh[j] = acc;
                }
            }
            float cc;
            if (r == 0) cc = 1.0f;
            else {
                float lp = 0.f;
                #pragma unroll
                for (int j = 0; j < 16; ++j) lp += vs[j] * xh[j];
                if constexpr (LPO >= 2) lp += __shfl_xor(lp, 1, 64);
                if constexpr (LPO >= 4) lp += __shfl_xor(lp, 2, 64);
                float ev = act ? __expf(lp) : 0.f;
                float tot = ev;
                tot += __shfl_xor(tot,1,64); tot += __shfl_xor(tot,2,64);
                tot += __shfl_xor(tot,4,64); tot += __shfl_xor(tot,8,64);
                tot += __shfl_xor(tot,16,64); tot += __shfl_xor(tot,32,64);
                cc = ev * (float)LPO / tot;
            }
            #pragma unroll
            for (int j = 0; j < 16; ++j) sacc[j] += cc * xh[j];
        }
        if (r == 0) {
            #pragma unroll
            for (int j = 0; j < 16; ++j) sacc[j] *= (1.0f / O);
        }
        float n2 = 0.f;
        #pragma unroll
        for (int j = 0; j < 16; ++j) n2 += sacc[j] * sacc[j];
        if constexpr (LPO >= 2) n2 += __shfl_xor(n2, 1, 64);
        if constexpr (LPO >= 4) n2 += __shfl_xor(n2, 2, 64);
        float nrm = sqrtf(n2);
        float scale = n2 / ((1.f + n2) * (nrm + 1e-8f));
        if (r < 2) {
            #pragma unroll
            for (int j = 0; j < 16; ++j) vs[j] += scale * sacc[j];
        } else {
            if constexpr (FINAL) {
                float q = 0.f;
                #pragma unroll
                for (int j = 0; j < 16; ++j) { float vj = scale*sacc[j]; q += vj*vj; }
                if constexpr (LPO >= 2) q += __shfl_xor(q, 1, 64);
                if constexpr (LPO >= 4) q += __shfl_xor(q, 2, 64);
                if (act && (l % LPO) == 0) out[(size_t)e * O + o] = sqrtf(q);
            } else {
                __syncthreads();
                if (act) {
                    #pragma unroll
                    for (int j = 0; j < 16; ++j) hl[o * Do + d0 + j] = scale * sacc[j];
                }
                __syncthreads();
            }
        }
    }
}

__global__ __launch_bounds__(256) void fb_caps(const float* __restrict__ x,
                                               const float* __restrict__ W0,
                                               const float* __restrict__ W1,
                                               const float* __restrict__ W2,
                                               float* __restrict__ out) {
    __shared__ float hsh[4][1024];
    const int w = threadIdx.x >> 6;
    const int l = threadIdx.x & 63;
    const int e = blockIdx.x * 4 + w;
    float* hl = hsh[w];
    const float4* xr = (const float4*)(x + (size_t)e * 1024);
    float4* h4 = (float4*)hl;
    #pragma unroll
    for (int k = 0; k < 4; ++k) h4[l + 64 * k] = xr[l + 64 * k];
    __syncthreads();
    fb_layer<128, 8, 64, 16, false>(W0, hl, out, e, l);
    fb_layer<64, 16, 32, 32, false>(W1, hl, out, e, l);
    fb_layer<32, 32, 10, 64, true >(W2, hl, out, e, l);
}

extern "C" void kernel_launch(void* const* d_in, const int* in_sizes, int n_in,
                              void* d_out, int out_size, void* d_ws, size_t ws_size,
                              hipStream_t stream) {
    const float* x  = (const float*)d_in[0];
    const float* W0 = (const float*)d_in[1];
    const float* W1 = (const float*)d_in[2];
    const float* W2 = (const float*)d_in[3];
    float* out = (float*)d_out;

    const size_t PS = (size_t)1024*8*1024;     // 8 partials x 1024 el x 1024
    const size_t need = (PS + 3u*1024*1024) * sizeof(float);   // ~46 MB
    if (ws_size < need) {                       // safety net: proven slow path
        fb_caps<<<256, 256, 0, stream>>>(x, W0, W1, W2, out);
        return;
    }

    float* ps = (float*)d_ws;
    float* vs = ps + PS;
    float* h1 = vs + (size_t)1024*1024;
    float* h2 = h1 + (size_t)1024*1024;
    dim3 g(32, 8);

    // layer 0: I=128 Di=8 O=64 Do=16, CI=2, dbuf
    k_contract<128,8,64,16,8,2,2,false><<<g,512,0,stream>>>(W0, x, nullptr, ps);
    k_squash<64,16,8,0><<<256,256,0,stream>>>(ps, vs, nullptr);
    k_contract<128,8,64,16,8,2,2,true ><<<g,512,0,stream>>>(W0, x, vs, ps);
    k_squash<64,16,8,1><<<256,256,0,stream>>>(ps, vs, nullptr);
    k_contract<128,8,64,16,8,2,2,true ><<<g,512,0,stream>>>(W0, x, vs, ps);
    k_squash<64,16,8,2><<<256,256,0,stream>>>(ps, vs, h1);

    // layer 1: I=64 Di=16 O=32 Do=32, CI=1, dbuf
    k_contract<64,16,32,32,8,1,2,false><<<g,512,0,stream>>>(W1, h1, nullptr, ps);
    k_squash<32,32,8,0><<<256,256,0,stream>>>(ps, vs, nullptr);
    k_contract<64,16,32,32,8,1,2,true ><<<g,512,0,stream>>>(W1, h1, vs, ps);
    k_squash<32,32,8,1><<<256,256,0,stream>>>(ps, vs, nullptr);
    k_contract<64,16,32,32,8,1,2,true ><<<g,512,0,stream>>>(W1, h1, vs, ps);
    k_squash<32,32,8,2><<<256,256,0,stream>>>(ps, vs, h2);

    // layer 2: I=32 Di=32 O=10 Do=64, CI=1, single-buffer (80KB slab)
    k_contract<32,32,10,64,8,1,1,false><<<g,512,0,stream>>>(W2, h2, nullptr, ps);
    k_squash<10,64,8,0><<<256,256,0,stream>>>(ps, vs, nullptr);
    k_contract<32,32,10,64,8,1,1,true ><<<g,512,0,stream>>>(W2, h2, vs, ps);
    k_squash<10,64,8,1><<<256,256,0,stream>>>(ps, vs, nullptr);
    k_contract<32,32,10,64,8,1,1,true ><<<g,512,0,stream>>>(W2, h2, vs, ps);
    k_squash<10,64,8,3><<<256,256,0,stream>>>(ps, vs, out);
}

// Round 5
// 1679.972 us; speedup vs baseline: 3.2460x; 1.7400x over previous
//
#include <hip/hip_runtime.h>
#include <math.h>

typedef unsigned int u32;

// ---------- bf16 helpers ----------
__device__ __forceinline__ u32 pk2(float a, float b){
    u32 ua=__float_as_uint(a), ub=__float_as_uint(b);
    u32 ra=(ua + 0x7fffu + ((ua>>16)&1u))>>16;
    u32 rb=(ub + 0x7fffu + ((ub>>16)&1u))>>16;
    return ra | (rb<<16);
}
__device__ __forceinline__ float lo16(u32 p){ return __uint_as_float(p<<16); }
__device__ __forceinline__ float hi16(u32 p){ return __uint_as_float(p & 0xffff0000u); }

// ---------- W convert: fp32 [o][i][jg][c] -> bf16 pairs, layout [i][jg][cb][o][4dw] ----------
template<int I,int Di,int O,int Do>
__global__ void k_conv(const float* __restrict__ W, u32* __restrict__ Wb){
    constexpr int CB = Di/8;
    const int n = O*I*Do*Di/2;
    for (int t = blockIdx.x*blockDim.x+threadIdx.x; t < n; t += gridDim.x*blockDim.x){
        int cw = t & 3;
        int u4 = t >> 2;
        int o  = u4 % O;
        int r1 = u4 / O;
        int cb = r1 % CB;
        int r2 = r1 / CB;
        int jg = r2 % Do;
        int i  = r2 / Do;
        int c  = cb*8 + cw*2;
        const float* s = W + ((size_t)(o*I + i)*Do + jg)*Di + c;
        Wb[t] = pk2(s[0], s[1]);
    }
}

// ---------- fused layer ----------
// Block: 8 waves, E=4 elements. Wave w: i_loc = w%WI (i within chunk),
// e-range e0=(w/WI)*Ew, Ew=4/(8/WI). Lane l: o=l/LPO, d0=(l%LPO)*16.
// X[e][16l + ((j+(l>>1))&15)]: staggered slot (2 lanes/bank on atomics = free).
// vs (logit state, affine identity) time-shares X with s.
template<int I,int Di,int O,int Do,int WI,int FIN>
__device__ __forceinline__ void run_layer(const u32* __restrict__ Wb,
    u32* slab, float (*X)[1024], u32 (*hp)[512], float* __restrict__ out,
    int bid, int w, int l, int tid)
{
    constexpr int CB  = Di/8;
    constexpr int ES  = 8/WI;
    constexpr int Ew  = 4/ES;
    constexpr int NCH = I/WI;
    constexpr int SLABDW = WI*Do*CB*O*4;
    constexpr int STG = SLABDW/(512*4);
    constexpr int LPO = Do/16;
    constexpr int ACT = O*LPO;

    const int i_loc = w % WI;
    const int e0 = (w/WI)*Ew;
    const int o  = l/LPO;
    const bool act = l < ACT;
    const int oa = act ? o : 0;
    const int da = act ? (l%LPO)*16 : 0;
    const int xrow = 16*l;                 // == oa*Do+da for active lanes
    const int st = (l>>1);                 // stagger

    uint4 gv[STG];
    auto gload = [&](int ch){
        const uint4* src = (const uint4*)Wb + (size_t)ch*(SLABDW/4);
        #pragma unroll
        for (int k=0;k<STG;++k) gv[k] = src[tid + 512*k];
    };

    float sacc[Ew][16];
    u32 vp[Ew][8];

    for (int r=0;r<3;++r){
        gload(0);
        if (r>0){
            #pragma unroll
            for (int eu=0;eu<Ew;++eu)
                #pragma unroll
                for (int jj=0;jj<8;++jj){
                    float a = X[e0+eu][xrow + ((2*jj   + st)&15)];
                    float b = X[e0+eu][xrow + ((2*jj+1 + st)&15)];
                    vp[eu][jj] = pk2(a,b);
                }
        }
        __syncthreads();                       // vp reads done before zeroing
        for (int k=tid;k<4096;k+=512) ((float*)X)[k]=0.f;
        #pragma unroll
        for (int eu=0;eu<Ew;++eu)
            #pragma unroll
            for (int j=0;j<16;++j) sacc[eu][j]=0.f;
        __syncthreads();

        for (int ch=0; ch<NCH; ++ch){
            {   // write staged regs -> slab
                uint4* s4=(uint4*)slab;
                #pragma unroll
                for (int k=0;k<STG;++k) s4[tid+512*k]=gv[k];
            }
            __syncthreads();
            if (ch+1<NCH) gload(ch+1);         // async: lands during compute

            const int i = ch*WI + i_loc;
            // h fragment (wave-uniform LDS reads -> broadcast)
            float hreg[Ew][Di];
            #pragma unroll
            for (int eu=0;eu<Ew;++eu)
                #pragma unroll
                for (int kb=0;kb<Di/8;++kb){
                    uint4 hv = *(const uint4*)&hp[e0+eu][i*(Di/2)+4*kb];
                    hreg[eu][kb*8+0]=lo16(hv.x); hreg[eu][kb*8+1]=hi16(hv.x);
                    hreg[eu][kb*8+2]=lo16(hv.y); hreg[eu][kb*8+3]=hi16(hv.y);
                    hreg[eu][kb*8+4]=lo16(hv.z); hreg[eu][kb*8+5]=hi16(hv.z);
                    hreg[eu][kb*8+6]=lo16(hv.w); hreg[eu][kb*8+7]=hi16(hv.w);
                }

            float xh[Ew][16];
            #pragma unroll
            for (int eu=0;eu<Ew;++eu)
                #pragma unroll
                for (int j=0;j<16;++j) xh[eu][j]=0.f;

            const uint4* wb4 = (const uint4*)slab + i_loc*(Do*CB*O);
            #pragma unroll
            for (int j=0;j<16;++j){
                const int jg = da + j;
                #pragma unroll
                for (int cb=0;cb<CB;++cb){
                    uint4 wv = wb4[(jg*CB+cb)*O + oa];   // contiguous 1KB/wave
                    float w0=lo16(wv.x),w1=hi16(wv.x),w2=lo16(wv.y),w3=hi16(wv.y),
                          w4=lo16(wv.z),w5=hi16(wv.z),w6=lo16(wv.w),w7=hi16(wv.w);
                    #pragma unroll
                    for (int eu=0;eu<Ew;++eu)
                        xh[eu][j] += w0*hreg[eu][cb*8+0] + w1*hreg[eu][cb*8+1]
                                   + w2*hreg[eu][cb*8+2] + w3*hreg[eu][cb*8+3]
                                   + w4*hreg[eu][cb*8+4] + w5*hreg[eu][cb*8+5]
                                   + w6*hreg[eu][cb*8+6] + w7*hreg[eu][cb*8+7];
                }
            }

            float cc[Ew];
            if (r==0){
                #pragma unroll
                for (int eu=0;eu<Ew;++eu) cc[eu]=1.f;   // 1/O folded at squash
            } else {
                #pragma unroll
                for (int eu=0;eu<Ew;++eu){
                    float lp=0.f;
                    #pragma unroll
                    for (int jj=0;jj<8;++jj)
                        lp += lo16(vp[eu][jj])*xh[eu][2*jj] + hi16(vp[eu][jj])*xh[eu][2*jj+1];
                    if constexpr (LPO>=2) lp += __shfl_xor(lp,1,64);
                    if constexpr (LPO>=4) lp += __shfl_xor(lp,2,64);
                    float ev = act ? __expf(lp) : 0.f;
                    float tot=ev;                       // counts each o LPO times
                    tot+=__shfl_xor(tot,1,64);  tot+=__shfl_xor(tot,2,64);
                    tot+=__shfl_xor(tot,4,64);  tot+=__shfl_xor(tot,8,64);
                    tot+=__shfl_xor(tot,16,64); tot+=__shfl_xor(tot,32,64);
                    cc[eu] = ev*(float)LPO/tot;
                }
            }
            #pragma unroll
            for (int eu=0;eu<Ew;++eu)
                #pragma unroll
                for (int j=0;j<16;++j) sacc[eu][j] += cc[eu]*xh[eu][j];
            __syncthreads();                   // slab reads done before next stage
        }

        // cross-wave i-reduction into X (staggered: 2 lanes/bank)
        if (act){
            #pragma unroll
            for (int eu=0;eu<Ew;++eu)
                #pragma unroll
                for (int j=0;j<16;++j)
                    atomicAdd(&X[e0+eu][xrow + ((j+st)&15)], sacc[eu][j]);
        }
        __syncthreads();

        // squash: even wave w handles e=w/2 (always within its e-range)
        if ((w&1)==0 && (w>>1)>=e0 && (w>>1)<e0+Ew){
            const int e = w>>1, eu = e - e0;
            float s[16];
            #pragma unroll
            for (int j=0;j<16;++j){
                float t = X[e][xrow + ((j+st)&15)];
                if (r==0) t *= (1.0f/(float)O);
                s[j]=t;
            }
            float n2=0.f;
            #pragma unroll
            for (int j=0;j<16;++j) n2 += s[j]*s[j];
            if constexpr (LPO>=2) n2 += __shfl_xor(n2,1,64);
            if constexpr (LPO>=4) n2 += __shfl_xor(n2,2,64);
            float nrm   = sqrtf(n2);
            float scale = n2/((1.f+n2)*(nrm+1e-8f));
            if (r<2){
                if (act){
                    #pragma unroll
                    for (int j=0;j<16;++j){
                        float vso = (r==0)?0.f:((j&1)? hi16(vp[eu][j>>1]) : lo16(vp[eu][j>>1]));
                        X[e][xrow + ((j+st)&15)] = vso + scale*s[j];
                    }
                }
            } else if constexpr (FIN==0){
                if (act){
                    #pragma unroll
                    for (int k=0;k<8;++k)
                        hp[e][l*8+k] = pk2(scale*s[2*k], scale*s[2*k+1]);
                }
            } else {
                if (act && (l%LPO)==0)
                    out[((size_t)(bid*4+e))*O + o] = scale*nrm;   // ||squash(s)||
            }
        }
        __syncthreads();
    }
}

__global__ __launch_bounds__(512,1) void caps_main(
    const float* __restrict__ x, const u32* __restrict__ Wb0,
    const u32* __restrict__ Wb1, const u32* __restrict__ Wb2,
    float* __restrict__ out)
{
    __shared__ u32   slab[32768];   // 128KB W chunk
    __shared__ float X[4][1024];    // 16KB vs/s (time-shared)
    __shared__ u32   hp[4][512];    // 8KB h (bf16 pairs)

    const int tid = threadIdx.x;
    const int w = tid>>6, l = tid&63;
    const int bid = blockIdx.x;

    {   // pack x -> hp
        const float2* xs = (const float2*)(x + (size_t)bid*4*1024);
        for (int k = tid; k < 2048; k += 512){
            float2 f = xs[k];
            ((u32*)hp)[k] = pk2(f.x, f.y);
        }
    }
    __syncthreads();

    run_layer<128, 8,64,16,4,0>(Wb0, slab, X, hp, out, bid, w, l, tid);
    run_layer< 64,16,32,32,4,0>(Wb1, slab, X, hp, out, bid, w, l, tid);
    run_layer< 32,32,10,64,2,1>(Wb2, slab, X, hp, out, bid, w, l, tid);
}

// ---------------- fallback (round-2 kernel, known-pass) ----------------
template<int I, int Di, int O, int Do, bool FINAL>
__device__ __forceinline__ void fb_layer(const float* __restrict__ W, float* __restrict__ hl,
                                         float* __restrict__ out, int e, int l) {
    constexpr int LPO = Do / 16;
    constexpr int ACT = O * LPO;
    const int o  = l / LPO;
    const int d0 = (l % LPO) * 16;
    const bool act = (l < ACT);
    float vs[16];
    #pragma unroll
    for (int j = 0; j < 16; ++j) vs[j] = 0.f;
    for (int r = 0; r < 3; ++r) {
        float sacc[16];
        #pragma unroll
        for (int j = 0; j < 16; ++j) sacc[j] = 0.f;
        for (int i = 0; i < I; ++i) {
            if ((i & 15) == 0) __syncthreads();
            float xh[16];
            #pragma unroll
            for (int j = 0; j < 16; ++j) xh[j] = 0.f;
            if (act) {
                const float* wb = W + ((size_t)(o * I + i) * Do + d0) * Di;
                #pragma unroll
                for (int j = 0; j < 16; ++j) {
                    const float4* wr = (const float4*)(wb + j * Di);
                    float acc = 0.f;
                    #pragma unroll
                    for (int c4 = 0; c4 < Di / 4; ++c4) {
                        float4 wv = wr[c4];
                        float4 hv = *(const float4*)(hl + i * Di + c4 * 4);
                        acc += wv.x*hv.x + wv.y*hv.y + wv.z*hv.z + wv.w*hv.w;
                    }
                    xh[j] = acc;
                }
            }
            float cc;
            if (r == 0) cc = 1.0f;
            else {
                float lp = 0.f;
                #pragma unroll
                for (int j = 0; j < 16; ++j) lp += vs[j] * xh[j];
                if constexpr (LPO >= 2) lp += __shfl_xor(lp, 1, 64);
                if constexpr (LPO >= 4) lp += __shfl_xor(lp, 2, 64);
                float ev = act ? __expf(lp) : 0.f;
                float tot = ev;
                tot += __shfl_xor(tot,1,64); tot += __shfl_xor(tot,2,64);
                tot += __shfl_xor(tot,4,64); tot += __shfl_xor(tot,8,64);
                tot += __shfl_xor(tot,16,64); tot += __shfl_xor(tot,32,64);
                cc = ev * (float)LPO / tot;
            }
            #pragma unroll
            for (int j = 0; j < 16; ++j) sacc[j] += cc * xh[j];
        }
        if (r == 0) {
            #pragma unroll
            for (int j = 0; j < 16; ++j) sacc[j] *= (1.0f / O);
        }
        float n2 = 0.f;
        #pragma unroll
        for (int j = 0; j < 16; ++j) n2 += sacc[j] * sacc[j];
        if constexpr (LPO >= 2) n2 += __shfl_xor(n2, 1, 64);
        if constexpr (LPO >= 4) n2 += __shfl_xor(n2, 2, 64);
        float nrm = sqrtf(n2);
        float scale = n2 / ((1.f + n2) * (nrm + 1e-8f));
        if (r < 2) {
            #pragma unroll
            for (int j = 0; j < 16; ++j) vs[j] += scale * sacc[j];
        } else {
            if constexpr (FINAL) {
                float q = 0.f;
                #pragma unroll
                for (int j = 0; j < 16; ++j) { float vj = scale*sacc[j]; q += vj*vj; }
                if constexpr (LPO >= 2) q += __shfl_xor(q, 1, 64);
                if constexpr (LPO >= 4) q += __shfl_xor(q, 2, 64);
                if (act && (l % LPO) == 0) out[(size_t)e * O + o] = sqrtf(q);
            } else {
                __syncthreads();
                if (act) {
                    #pragma unroll
                    for (int j = 0; j < 16; ++j) hl[o * Do + d0 + j] = scale * sacc[j];
                }
                __syncthreads();
            }
        }
    }
}

__global__ __launch_bounds__(256) void fb_caps(const float* __restrict__ x,
                                               const float* __restrict__ W0,
                                               const float* __restrict__ W1,
                                               const float* __restrict__ W2,
                                               float* __restrict__ out) {
    __shared__ float hsh[4][1024];
    const int w = threadIdx.x >> 6;
    const int l = threadIdx.x & 63;
    const int e = blockIdx.x * 4 + w;
    float* hl = hsh[w];
    const float4* xr = (const float4*)(x + (size_t)e * 1024);
    float4* h4 = (float4*)hl;
    #pragma unroll
    for (int k = 0; k < 4; ++k) h4[l + 64 * k] = xr[l + 64 * k];
    __syncthreads();
    fb_layer<128, 8, 64, 16, false>(W0, hl, out, e, l);
    fb_layer<64, 16, 32, 32, false>(W1, hl, out, e, l);
    fb_layer<32, 32, 10, 64, true >(W2, hl, out, e, l);
}

extern "C" void kernel_launch(void* const* d_in, const int* in_sizes, int n_in,
                              void* d_out, int out_size, void* d_ws, size_t ws_size,
                              hipStream_t stream) {
    const float* x  = (const float*)d_in[0];   // [1024,1024]
    const float* W0 = (const float*)d_in[1];   // [64,128,16,8]
    const float* W1 = (const float*)d_in[2];   // [32,64,32,16]
    const float* W2 = (const float*)d_in[3];   // [10,32,64,32]
    float* out = (float*)d_out;                // [1024,10]

    const size_t DW0 = (size_t)64*128*16*8/2;   // 524288
    const size_t DW1 = (size_t)32*64*32*16/2;   // 524288
    const size_t DW2 = (size_t)10*32*64*32/2;   // 327680
    const size_t need = (DW0+DW1+DW2)*4;        // 5505024 B

    if (ws_size < need) {                       // safety net: proven slow path
        fb_caps<<<256, 256, 0, stream>>>(x, W0, W1, W2, out);
        return;
    }

    u32* Wb0 = (u32*)d_ws;
    u32* Wb1 = Wb0 + DW0;
    u32* Wb2 = Wb1 + DW1;

    k_conv<128, 8,64,16><<<512,256,0,stream>>>(W0, Wb0);
    k_conv< 64,16,32,32><<<512,256,0,stream>>>(W1, Wb1);
    k_conv< 32,32,10,64><<<512,256,0,stream>>>(W2, Wb2);

    caps_main<<<256, 512, 0, stream>>>(x, Wb0, Wb1, Wb2, out);
}

// Round 6
// 720.171 us; speedup vs baseline: 7.5721x; 2.3327x over previous
//
#include <hip/hip_runtime.h>
#include <math.h>

typedef unsigned int u32;

// ---------- bf16 helpers ----------
__device__ __forceinline__ u32 pk2(float a, float b){
    u32 ua=__float_as_uint(a), ub=__float_as_uint(b);
    u32 ra=(ua + 0x7fffu + ((ua>>16)&1u))>>16;
    u32 rb=(ub + 0x7fffu + ((ub>>16)&1u))>>16;
    return ra | (rb<<16);
}
__device__ __forceinline__ float lo16(u32 p){ return __uint_as_float(p<<16); }
__device__ __forceinline__ float hi16(u32 p){ return __uint_as_float(p & 0xffff0000u); }

// async global->LDS, 16B per lane; LDS dest = wave-uniform base + lane*16
__device__ __forceinline__ void gll16(const u32* gp, u32* lp){
    __builtin_amdgcn_global_load_lds((const __attribute__((address_space(1))) void*)gp,
                                     (__attribute__((address_space(3))) void*)lp,
                                     16, 0, 0);
}

// ---------- W convert: fp32 [o][i][jg][c] -> bf16 pairs, layout [i][jj][cb][q][o] ----------
// jg = q*16 + jj (q = lane%LPO part, jj = per-lane j loop 0..15), c = cb*8 + cw*2.
template<int I,int Di,int O,int Do>
__global__ void k_conv(const float* __restrict__ W, u32* __restrict__ Wb){
    constexpr int CB = Di/8, LPO = Do/16;
    const int n = O*I*Do*Di/2;
    for (int t = blockIdx.x*blockDim.x+threadIdx.x; t < n; t += gridDim.x*blockDim.x){
        int cw = t & 3;
        int u4 = t >> 2;
        int o  = u4 % O;
        int r1 = u4 / O;
        int q  = r1 % LPO;
        int r2 = r1 / LPO;
        int cb = r2 % CB;
        int r3 = r2 / CB;
        int jj = r3 & 15;
        int i  = r3 >> 4;
        int jg = q*16 + jj;
        int c  = cb*8 + cw*2;
        const float* s = W + ((size_t)(o*I + i)*Do + jg)*Di + c;
        Wb[t] = pk2(s[0], s[1]);
    }
}

// ---------- fused layer ----------
// 8 waves: i_loc = w%WI, e-group = w/WI owning Ew=4/(8/WI) elements.
// Lane: o = l/LPO, d-block q = l%LPO (16 d's). W chunk staged via global_load_lds.
// Cross-wave i-reduction via red buffer ALIASING slab (dead between passes).
template<int I,int Di,int O,int Do,int WI,int NBUF,int FIN>
__device__ __forceinline__ void run_layer(const u32* __restrict__ Wb,
    u32* slab, float (*X)[1024], u32 (*hp)[512], float* __restrict__ out,
    int bid, int w, int l, int tid)
{
    constexpr int CB   = Di/8;
    constexpr int LPO  = Do/16;
    constexpr int ACT  = O*LPO;
    constexpr int ES   = 8/WI;
    constexpr int Ew   = 4/ES;
    constexpr int NCH  = I/WI;
    constexpr int UI   = 16*CB*LPO*O;        // uint4 per i-slice
    constexpr int CHDW = WI*UI*4;            // u32 per chunk
    constexpr int ROUNDS = CHDW/2048;        // 512 thr x 16B staging rounds
    static_assert(Ew >= 1, "element split");

    const int i_loc = w % WI;
    const int e0    = (w/WI)*Ew;
    const bool act  = l < ACT;
    const int qL    = act ? (l % LPO) : 0;
    const int oaL   = act ? (l / LPO) : 0;
    const int lnoff = qL*O + oaL;            // per-lane slab offset (uint4)
    float* red = (float*)slab;               // aliases slab between passes

    for (int r = 0; r < 3; ++r){
        u32 vp[Ew][8];
        if (r > 0){
            #pragma unroll
            for (int eu=0; eu<Ew; ++eu)
                #pragma unroll
                for (int jj=0; jj<8; ++jj)
                    vp[eu][jj] = pk2(X[e0+eu][16*l + 2*jj], X[e0+eu][16*l + 2*jj+1]);
        }

        float sacc[Ew][16];
        #pragma unroll
        for (int eu=0; eu<Ew; ++eu)
            #pragma unroll
            for (int j=0; j<16; ++j) sacc[eu][j] = 0.f;

        auto stage = [&](int ch, int buf){
            const u32* g = Wb + (size_t)ch*CHDW + tid*4;
            u32* ld      = slab + buf*CHDW + w*256;
            #pragma unroll
            for (int rd=0; rd<ROUNDS; ++rd)
                gll16(g + rd*2048, ld + rd*2048);
        };

        auto compute = [&](int ch, int buf){
            const int i = ch*WI + i_loc;
            float hreg[Ew][Di];
            #pragma unroll
            for (int eu=0; eu<Ew; ++eu)
                #pragma unroll
                for (int kb=0; kb<Di/8; ++kb){
                    uint4 hv = *(const uint4*)&hp[e0+eu][i*(Di/2) + kb*4];
                    hreg[eu][kb*8+0]=lo16(hv.x); hreg[eu][kb*8+1]=hi16(hv.x);
                    hreg[eu][kb*8+2]=lo16(hv.y); hreg[eu][kb*8+3]=hi16(hv.y);
                    hreg[eu][kb*8+4]=lo16(hv.z); hreg[eu][kb*8+5]=hi16(hv.z);
                    hreg[eu][kb*8+6]=lo16(hv.w); hreg[eu][kb*8+7]=hi16(hv.w);
                }

            float xh[Ew][16];
            #pragma unroll
            for (int eu=0; eu<Ew; ++eu)
                #pragma unroll
                for (int j=0; j<16; ++j) xh[eu][j] = 0.f;

            const uint4* wb4 = (const uint4*)(slab + (size_t)buf*CHDW) + i_loc*UI + lnoff;
            #pragma unroll
            for (int j=0; j<16; ++j){
                #pragma unroll
                for (int cb=0; cb<CB; ++cb){
                    uint4 wv = wb4[(j*CB + cb)*(LPO*O)];
                    float w0=lo16(wv.x),w1=hi16(wv.x),w2=lo16(wv.y),w3=hi16(wv.y),
                          w4=lo16(wv.z),w5=hi16(wv.z),w6=lo16(wv.w),w7=hi16(wv.w);
                    #pragma unroll
                    for (int eu=0; eu<Ew; ++eu)
                        xh[eu][j] += w0*hreg[eu][cb*8+0] + w1*hreg[eu][cb*8+1]
                                   + w2*hreg[eu][cb*8+2] + w3*hreg[eu][cb*8+3]
                                   + w4*hreg[eu][cb*8+4] + w5*hreg[eu][cb*8+5]
                                   + w6*hreg[eu][cb*8+6] + w7*hreg[eu][cb*8+7];
                }
            }

            float cc[Ew];
            if (r == 0){
                #pragma unroll
                for (int eu=0; eu<Ew; ++eu) cc[eu] = 1.f;   // 1/O folded at squash
            } else {
                #pragma unroll
                for (int eu=0; eu<Ew; ++eu){
                    float lp = 0.f;
                    #pragma unroll
                    for (int jj=0; jj<8; ++jj)
                        lp += lo16(vp[eu][jj])*xh[eu][2*jj] + hi16(vp[eu][jj])*xh[eu][2*jj+1];
                    if constexpr (LPO>=2) lp += __shfl_xor(lp,1,64);
                    if constexpr (LPO>=4) lp += __shfl_xor(lp,2,64);
                    float ev = act ? __expf(lp) : 0.f;
                    float tot = ev;                         // each o counted LPO times
                    tot+=__shfl_xor(tot,1,64);  tot+=__shfl_xor(tot,2,64);
                    tot+=__shfl_xor(tot,4,64);  tot+=__shfl_xor(tot,8,64);
                    tot+=__shfl_xor(tot,16,64); tot+=__shfl_xor(tot,32,64);
                    cc[eu] = ev*(float)LPO/tot;
                }
            }
            #pragma unroll
            for (int eu=0; eu<Ew; ++eu)
                #pragma unroll
                for (int j=0; j<16; ++j) sacc[eu][j] += cc[eu]*xh[eu][j];
        };

        if constexpr (NBUF == 2){
            stage(0, 0);
            __syncthreads();
            for (int ch=0; ch<NCH; ++ch){
                if (ch+1 < NCH) stage(ch+1, (ch+1)&1);   // issue before compute; drained at barrier
                compute(ch, ch&1);
                __syncthreads();
            }
        } else {
            for (int ch=0; ch<NCH; ++ch){
                stage(ch, 0);
                __syncthreads();
                compute(ch, 0);
                __syncthreads();
            }
        }

        // per-wave partials -> red (aliases slab; all staging drained)
        if (act){
            #pragma unroll
            for (int eu=0; eu<Ew; ++eu)
                #pragma unroll
                for (int j=0; j<16; ++j)
                    red[((e0+eu)*WI + i_loc)*1024 + 16*l + j] = sacc[eu][j];
        }
        __syncthreads();

        // 512-thread stride-1 reduce over WI partials (in place at p=0)
        for (int t = tid; t < 4096; t += 512){
            int e = t >> 10, k = t & 1023;
            float s = 0.f;
            #pragma unroll
            for (int p=0; p<WI; ++p) s += red[(e*WI + p)*1024 + k];
            red[e*WI*1024 + k] = s;
        }
        __syncthreads();

        // squash: wave e<4 handles element e
        if (w < 4){
            const int e = w;
            float s[16];
            #pragma unroll
            for (int j=0; j<16; ++j){
                float t = red[e*WI*1024 + 16*l + j];
                if (r == 0) t *= (1.0f/(float)O);
                s[j] = t;
            }
            float n2 = 0.f;
            #pragma unroll
            for (int j=0; j<16; ++j) n2 += s[j]*s[j];
            if constexpr (LPO>=2) n2 += __shfl_xor(n2,1,64);
            if constexpr (LPO>=4) n2 += __shfl_xor(n2,2,64);
            float nrm   = sqrtf(n2);
            float scale = n2/((1.f+n2)*(nrm+1e-8f));

            if (r < 2){
                if (act){
                    #pragma unroll
                    for (int j=0; j<16; ++j){
                        float old = (r==0) ? 0.f : X[e][16*l + j];
                        X[e][16*l + j] = old + scale*s[j];   // vs += v (affine-logit carry)
                    }
                }
            } else if constexpr (FIN == 0){
                if (act){
                    #pragma unroll
                    for (int k=0; k<8; ++k)
                        hp[e][8*l + k] = pk2(scale*s[2*k], scale*s[2*k+1]);
                }
            } else {
                float q = 0.f;
                #pragma unroll
                for (int j=0; j<16; ++j){ float vj = scale*s[j]; q += vj*vj; }
                if constexpr (LPO>=2) q += __shfl_xor(q,1,64);
                if constexpr (LPO>=4) q += __shfl_xor(q,2,64);
                if (act && (l % LPO) == 0)
                    out[(size_t)(bid*4 + e)*O + (l/LPO)] = sqrtf(q);
            }
        }
        __syncthreads();
    }
}

__global__ __launch_bounds__(512,2) void caps_main(
    const float* __restrict__ x, const u32* __restrict__ Wb0,
    const u32* __restrict__ Wb1, const u32* __restrict__ Wb2,
    float* __restrict__ out)
{
    __shared__ __align__(16) u32 slab[32768];   // 128KB W chunks (red aliases)
    __shared__ __align__(16) float X[4][1024];  // 16KB vs state
    __shared__ __align__(16) u32 hp[4][512];    // 8KB h (bf16 pairs)

    const int tid = threadIdx.x;
    const int w = tid>>6, l = tid&63;
    const int bid = blockIdx.x;

    {   // pack x -> hp (bf16)
        const float2* xs = (const float2*)(x + (size_t)bid*4*1024);
        for (int k = tid; k < 2048; k += 512){
            float2 f = xs[k];
            ((u32*)hp)[k] = pk2(f.x, f.y);
        }
    }
    __syncthreads();

    run_layer<128, 8,64,16,4,2,0>(Wb0, slab, X, hp, out, bid, w, l, tid);
    run_layer< 64,16,32,32,2,2,0>(Wb1, slab, X, hp, out, bid, w, l, tid);
    run_layer< 32,32,10,64,2,1,1>(Wb2, slab, X, hp, out, bid, w, l, tid);
}

// ---------------- fallback (round-2 kernel, known-pass) ----------------
template<int I, int Di, int O, int Do, bool FINAL>
__device__ __forceinline__ void fb_layer(const float* __restrict__ W, float* __restrict__ hl,
                                         float* __restrict__ out, int e, int l) {
    constexpr int LPO = Do / 16;
    constexpr int ACT = O * LPO;
    const int o  = l / LPO;
    const int d0 = (l % LPO) * 16;
    const bool act = (l < ACT);
    float vs[16];
    #pragma unroll
    for (int j = 0; j < 16; ++j) vs[j] = 0.f;
    for (int r = 0; r < 3; ++r) {
        float sacc[16];
        #pragma unroll
        for (int j = 0; j < 16; ++j) sacc[j] = 0.f;
        for (int i = 0; i < I; ++i) {
            if ((i & 15) == 0) __syncthreads();
            float xh[16];
            #pragma unroll
            for (int j = 0; j < 16; ++j) xh[j] = 0.f;
            if (act) {
                const float* wb = W + ((size_t)(o * I + i) * Do + d0) * Di;
                #pragma unroll
                for (int j = 0; j < 16; ++j) {
                    const float4* wr = (const float4*)(wb + j * Di);
                    float acc = 0.f;
                    #pragma unroll
                    for (int c4 = 0; c4 < Di / 4; ++c4) {
                        float4 wv = wr[c4];
                        float4 hv = *(const float4*)(hl + i * Di + c4 * 4);
                        acc += wv.x*hv.x + wv.y*hv.y + wv.z*hv.z + wv.w*hv.w;
                    }
                    xh[j] = acc;
                }
            }
            float cc;
            if (r == 0) cc = 1.0f;
            else {
                float lp = 0.f;
                #pragma unroll
                for (int j = 0; j < 16; ++j) lp += vs[j] * xh[j];
                if constexpr (LPO >= 2) lp += __shfl_xor(lp, 1, 64);
                if constexpr (LPO >= 4) lp += __shfl_xor(lp, 2, 64);
                float ev = act ? __expf(lp) : 0.f;
                float tot = ev;
                tot += __shfl_xor(tot,1,64); tot += __shfl_xor(tot,2,64);
                tot += __shfl_xor(tot,4,64); tot += __shfl_xor(tot,8,64);
                tot += __shfl_xor(tot,16,64); tot += __shfl_xor(tot,32,64);
                cc = ev * (float)LPO / tot;
            }
            #pragma unroll
            for (int j = 0; j < 16; ++j) sacc[j] += cc * xh[j];
        }
        if (r == 0) {
            #pragma unroll
            for (int j = 0; j < 16; ++j) sacc[j] *= (1.0f / O);
        }
        float n2 = 0.f;
        #pragma unroll
        for (int j = 0; j < 16; ++j) n2 += sacc[j] * sacc[j];
        if constexpr (LPO >= 2) n2 += __shfl_xor(n2, 1, 64);
        if constexpr (LPO >= 4) n2 += __shfl_xor(n2, 2, 64);
        float nrm = sqrtf(n2);
        float scale = n2 / ((1.f + n2) * (nrm + 1e-8f));
        if (r < 2) {
            #pragma unroll
            for (int j = 0; j < 16; ++j) vs[j] += scale * sacc[j];
        } else {
            if constexpr (FINAL) {
                float q = 0.f;
                #pragma unroll
                for (int j = 0; j < 16; ++j) { float vj = scale*sacc[j]; q += vj*vj; }
                if constexpr (LPO >= 2) q += __shfl_xor(q, 1, 64);
                if constexpr (LPO >= 4) q += __shfl_xor(q, 2, 64);
                if (act && (l % LPO) == 0) out[(size_t)e * O + o] = sqrtf(q);
            } else {
                __syncthreads();
                if (act) {
                    #pragma unroll
                    for (int j = 0; j < 16; ++j) hl[o * Do + d0 + j] = scale * sacc[j];
                }
                __syncthreads();
            }
        }
    }
}

__global__ __launch_bounds__(256) void fb_caps(const float* __restrict__ x,
                                               const float* __restrict__ W0,
                                               const float* __restrict__ W1,
                                               const float* __restrict__ W2,
                                               float* __restrict__ out) {
    __shared__ float hsh[4][1024];
    const int w = threadIdx.x >> 6;
    const int l = threadIdx.x & 63;
    const int e = blockIdx.x * 4 + w;
    float* hl = hsh[w];
    const float4* xr = (const float4*)(x + (size_t)e * 1024);
    float4* h4 = (float4*)hl;
    #pragma unroll
    for (int k = 0; k < 4; ++k) h4[l + 64 * k] = xr[l + 64 * k];
    __syncthreads();
    fb_layer<128, 8, 64, 16, false>(W0, hl, out, e, l);
    fb_layer<64, 16, 32, 32, false>(W1, hl, out, e, l);
    fb_layer<32, 32, 10, 64, true >(W2, hl, out, e, l);
}

extern "C" void kernel_launch(void* const* d_in, const int* in_sizes, int n_in,
                              void* d_out, int out_size, void* d_ws, size_t ws_size,
                              hipStream_t stream) {
    const float* x  = (const float*)d_in[0];   // [1024,1024]
    const float* W0 = (const float*)d_in[1];   // [64,128,16,8]
    const float* W1 = (const float*)d_in[2];   // [32,64,32,16]
    const float* W2 = (const float*)d_in[3];   // [10,32,64,32]
    float* out = (float*)d_out;                // [1024,10]

    const size_t DW0 = (size_t)64*128*16*8/2;   // u32 counts
    const size_t DW1 = (size_t)32*64*32*16/2;
    const size_t DW2 = (size_t)10*32*64*32/2;
    const size_t need = (DW0+DW1+DW2)*4;        // ~5.5 MB

    if (ws_size < need) {                       // safety net: proven slow path
        fb_caps<<<256, 256, 0, stream>>>(x, W0, W1, W2, out);
        return;
    }

    u32* Wb0 = (u32*)d_ws;
    u32* Wb1 = Wb0 + DW0;
    u32* Wb2 = Wb1 + DW1;

    k_conv<128, 8,64,16><<<512,256,0,stream>>>(W0, Wb0);
    k_conv< 64,16,32,32><<<512,256,0,stream>>>(W1, Wb1);
    k_conv< 32,32,10,64><<<512,256,0,stream>>>(W2, Wb2);

    caps_main<<<256, 512, 0, stream>>>(x, Wb0, Wb1, Wb2, out);
}

// Round 7
// 689.976 us; speedup vs baseline: 7.9034x; 1.0438x over previous
//
#include <hip/hip_runtime.h>
#include <math.h>

typedef unsigned int u32;

// ---------- bf16 helpers ----------
__device__ __forceinline__ u32 pk2(float a, float b){
    u32 ua=__float_as_uint(a), ub=__float_as_uint(b);
    u32 ra=(ua + 0x7fffu + ((ua>>16)&1u))>>16;
    u32 rb=(ub + 0x7fffu + ((ub>>16)&1u))>>16;
    return ra | (rb<<16);
}
__device__ __forceinline__ float lo16(u32 p){ return __uint_as_float(p<<16); }
__device__ __forceinline__ float hi16(u32 p){ return __uint_as_float(p & 0xffff0000u); }

// packed bf16x2 dot-accumulate: c += a.x*b.x + a.y*b.y
#if __has_builtin(__builtin_amdgcn_fdot2_f32_bf16)
__device__ __forceinline__ float dot2bf(u32 a, u32 b, float c){
    float d;
    asm("v_dot2_f32_bf16 %0, %1, %2, %3" : "=v"(d) : "v"(a), "v"(b), "v"(c));
    return d;
}
#else
__device__ __forceinline__ float dot2bf(u32 a, u32 b, float c){
    return fmaf(hi16(a), hi16(b), fmaf(lo16(a), lo16(b), c));
}
#endif

// ---------- W convert: fp32 [o][i][jg][c] -> bf16 pairs, layout [i][jj][cb][q][o] ----------
template<int I,int Di,int O,int Do>
__global__ void k_conv(const float* __restrict__ W, u32* __restrict__ Wb){
    constexpr int CB = Di/8, LPO = Do/16;
    const int n = O*I*Do*Di/2;
    for (int t = blockIdx.x*blockDim.x+threadIdx.x; t < n; t += gridDim.x*blockDim.x){
        int cw = t & 3;
        int u4 = t >> 2;
        int o  = u4 % O;
        int r1 = u4 / O;
        int q  = r1 % LPO;
        int r2 = r1 / LPO;
        int cb = r2 % CB;
        int r3 = r2 / CB;
        int jj = r3 & 15;
        int i  = r3 >> 4;
        int jg = q*16 + jj;
        int c  = cb*8 + cw*2;
        const float* s = W + ((size_t)(o*I + i)*Do + jg)*Di + c;
        Wb[t] = pk2(s[0], s[1]);
    }
}

// ---------- fused layer, direct-from-L2 W reads ----------
// 8 waves. WI waves split the i-axis (multiplicity-1 W reads); e-group w/WI owns
// Ew=4/(8/WI) elements. Lane l: o=l/LPO, d-block q=l%LPO (16 d's).
// W read straight from global (L2-resident) with a 2-group register pipeline.
// Per-pass cross-wave s-reduction: atomicAdd into lane-major SS[e][j*64+l].
// vs carry (affine-logit identity) in lane-major X[e][j*64+l].
template<int I,int Di,int O,int Do,int WI,int FIN>
__device__ __forceinline__ void run_layer(const u32* __restrict__ Wb,
    float (*X)[1024], float (*SS)[1024], u32 (*hp)[512], float* __restrict__ out,
    int bid, int w, int l, int tid)
{
    constexpr int CB  = Di/8;
    constexpr int LPO = Do/16;
    constexpr int ACT = O*LPO;
    constexpr int GR  = LPO*O;        // uint4 granule per (j,cb)
    constexpr int ES  = 8/WI;
    constexpr int Ew  = 4/ES;
    constexpr int NSL = 16*CB;        // uint4 slots per i per lane
    constexpr int NG  = NSL/4;        // groups of 4 slots
    static_assert(Ew >= 1, "");

    const int i_loc = w % WI;
    const int e0    = (w/WI)*Ew;
    const bool act  = l < ACT;
    const int qL    = act ? (l % LPO) : 0;
    const int oL    = act ? (l / LPO) : 0;
    const int lnoff = qL*O + oL;      // per-lane uint4 offset within granule
    const uint4* W4 = (const uint4*)Wb;

    for (int r = 0; r < 3; ++r){
        u32 vp[Ew][8];
        if (r > 0){
            #pragma unroll
            for (int eu=0; eu<Ew; ++eu)
                #pragma unroll
                for (int jj=0; jj<8; ++jj)
                    vp[eu][jj] = pk2(X[e0+eu][(2*jj)*64 + l], X[e0+eu][(2*jj+1)*64 + l]);
        }

        float sacc[Ew][16];
        #pragma unroll
        for (int eu=0; eu<Ew; ++eu)
            #pragma unroll
            for (int j=0; j<16; ++j) sacc[eu][j] = 0.f;

        for (int k = 0; k < I/WI; ++k){
            const int i = i_loc + WI*k;
            const size_t bi = (size_t)i*NSL*GR + lnoff;

            // h fragment, packed bf16 pairs (dot2 operand)
            u32 hk[Ew][Di/2];
            #pragma unroll
            for (int eu=0; eu<Ew; ++eu)
                #pragma unroll
                for (int t4=0; t4<Di/8; ++t4){
                    uint4 hv = *(const uint4*)&hp[e0+eu][i*(Di/2) + 4*t4];
                    hk[eu][4*t4+0]=hv.x; hk[eu][4*t4+1]=hv.y;
                    hk[eu][4*t4+2]=hv.z; hk[eu][4*t4+3]=hv.w;
                }

            float xh[Ew][16];
            #pragma unroll
            for (int eu=0; eu<Ew; ++eu)
                #pragma unroll
                for (int j=0; j<16; ++j) xh[eu][j] = 0.f;

            uint4 bufA[4], bufB[4];
            auto ldg = [&](int g, uint4 (&buf)[4]){
                #pragma unroll
                for (int s=0; s<4; ++s)
                    buf[s] = W4[bi + (size_t)(4*g+s)*GR];
            };
            auto cmp = [&](int g, uint4 (&buf)[4]){
                #pragma unroll
                for (int s=0; s<4; ++s){
                    const int slot = 4*g+s, j = slot/CB, cb = slot%CB;
                    #pragma unroll
                    for (int eu=0; eu<Ew; ++eu){
                        float t = xh[eu][j];
                        t = dot2bf(buf[s].x, hk[eu][cb*4+0], t);
                        t = dot2bf(buf[s].y, hk[eu][cb*4+1], t);
                        t = dot2bf(buf[s].z, hk[eu][cb*4+2], t);
                        t = dot2bf(buf[s].w, hk[eu][cb*4+3], t);
                        xh[eu][j] = t;
                    }
                }
            };

            ldg(0, bufA);
            #pragma unroll
            for (int g=0; g<NG; ++g){
                if (g & 1){ if (g+1<NG) ldg(g+1, bufA); cmp(g, bufB); }
                else      { if (g+1<NG) ldg(g+1, bufB); cmp(g, bufA); }
            }

            float cc[Ew];
            if (r == 0){
                #pragma unroll
                for (int eu=0; eu<Ew; ++eu) cc[eu] = 1.f;   // 1/O folded at squash
            } else {
                #pragma unroll
                for (int eu=0; eu<Ew; ++eu){
                    float lp = 0.f;
                    #pragma unroll
                    for (int jj=0; jj<8; ++jj)
                        lp += lo16(vp[eu][jj])*xh[eu][2*jj] + hi16(vp[eu][jj])*xh[eu][2*jj+1];
                    if constexpr (LPO>=2) lp += __shfl_xor(lp,1,64);
                    if constexpr (LPO>=4) lp += __shfl_xor(lp,2,64);
                    float ev = act ? __expf(lp) : 0.f;
                    float tot = ev;                          // each o counted LPO times
                    tot+=__shfl_xor(tot,1,64);  tot+=__shfl_xor(tot,2,64);
                    tot+=__shfl_xor(tot,4,64);  tot+=__shfl_xor(tot,8,64);
                    tot+=__shfl_xor(tot,16,64); tot+=__shfl_xor(tot,32,64);
                    cc[eu] = ev*(float)LPO/tot;
                }
            }
            #pragma unroll
            for (int eu=0; eu<Ew; ++eu)
                #pragma unroll
                for (int j=0; j<16; ++j) sacc[eu][j] += cc[eu]*xh[eu][j];
        }

        // cross-wave reduction (lane-major: 2 lanes/bank, conflict-free)
        if (act){
            #pragma unroll
            for (int eu=0; eu<Ew; ++eu)
                #pragma unroll
                for (int j=0; j<16; ++j)
                    atomicAdd(&SS[e0+eu][j*64 + l], sacc[eu][j]);
        }
        __syncthreads();

        // squash: wave e handles element e
        if (w < 4){
            const int e = w;
            float s[16];
            #pragma unroll
            for (int j=0; j<16; ++j){
                float t = SS[e][j*64 + l];
                if (r == 0) t *= (1.0f/(float)O);
                s[j] = t;
            }
            float n2 = 0.f;
            #pragma unroll
            for (int j=0; j<16; ++j) n2 += s[j]*s[j];
            if constexpr (LPO>=2) n2 += __shfl_xor(n2,1,64);
            if constexpr (LPO>=4) n2 += __shfl_xor(n2,2,64);
            float nrm   = sqrtf(n2);
            float scale = n2/((1.f+n2)*(nrm+1e-8f));

            if (r < 2){
                if (act){
                    #pragma unroll
                    for (int j=0; j<16; ++j){
                        float old = (r==0) ? 0.f : X[e][j*64 + l];
                        X[e][j*64 + l] = old + scale*s[j];   // vs += v
                    }
                }
            } else if constexpr (FIN == 0){
                if (act){
                    #pragma unroll
                    for (int kk=0; kk<8; ++kk)
                        hp[e][oL*(Do/2) + qL*8 + kk] = pk2(scale*s[2*kk], scale*s[2*kk+1]);
                }
            } else {
                float q = 0.f;
                #pragma unroll
                for (int j=0; j<16; ++j){ float vj = scale*s[j]; q += vj*vj; }
                if constexpr (LPO>=2) q += __shfl_xor(q,1,64);
                if constexpr (LPO>=4) q += __shfl_xor(q,2,64);
                if (act && (l % LPO) == 0)
                    out[(size_t)(bid*4 + e)*O + oL] = sqrtf(q);
            }
        }
        __syncthreads();
        // zero SS for next pass
        for (int t = tid; t < 4096; t += 512) ((float*)SS)[t] = 0.f;
        __syncthreads();
    }
}

__global__ __launch_bounds__(512,2) void caps_main(
    const float* __restrict__ x, const u32* __restrict__ Wb0,
    const u32* __restrict__ Wb1, const u32* __restrict__ Wb2,
    float* __restrict__ out)
{
    __shared__ __align__(16) float X[4][1024];   // vs state (lane-major)
    __shared__ __align__(16) float SS[4][1024];  // s accumulation (lane-major)
    __shared__ __align__(16) u32 hp[4][512];     // h (bf16 pairs)

    const int tid = threadIdx.x;
    const int w = tid>>6, l = tid&63;
    const int bid = blockIdx.x;

    {   // pack x -> hp (bf16), zero SS
        const float2* xs = (const float2*)(x + (size_t)bid*4*1024);
        for (int k = tid; k < 2048; k += 512){
            float2 f = xs[k];
            ((u32*)hp)[k] = pk2(f.x, f.y);
        }
        for (int k = tid; k < 4096; k += 512) ((float*)SS)[k] = 0.f;
    }
    __syncthreads();

    run_layer<128, 8,64,16,8,0>(Wb0, X, SS, hp, out, bid, w, l, tid);
    run_layer< 64,16,32,32,8,0>(Wb1, X, SS, hp, out, bid, w, l, tid);
    run_layer< 32,32,10,64,4,1>(Wb2, X, SS, hp, out, bid, w, l, tid);
}

// ---------------- fallback (round-2 kernel, known-pass) ----------------
template<int I, int Di, int O, int Do, bool FINAL>
__device__ __forceinline__ void fb_layer(const float* __restrict__ W, float* __restrict__ hl,
                                         float* __restrict__ out, int e, int l) {
    constexpr int LPO = Do / 16;
    constexpr int ACT = O * LPO;
    const int o  = l / LPO;
    const int d0 = (l % LPO) * 16;
    const bool act = (l < ACT);
    float vs[16];
    #pragma unroll
    for (int j = 0; j < 16; ++j) vs[j] = 0.f;
    for (int r = 0; r < 3; ++r) {
        float sacc[16];
        #pragma unroll
        for (int j = 0; j < 16; ++j) sacc[j] = 0.f;
        for (int i = 0; i < I; ++i) {
            if ((i & 15) == 0) __syncthreads();
            float xh[16];
            #pragma unroll
            for (int j = 0; j < 16; ++j) xh[j] = 0.f;
            if (act) {
                const float* wb = W + ((size_t)(o * I + i) * Do + d0) * Di;
                #pragma unroll
                for (int j = 0; j < 16; ++j) {
                    const float4* wr = (const float4*)(wb + j * Di);
                    float acc = 0.f;
                    #pragma unroll
                    for (int c4 = 0; c4 < Di / 4; ++c4) {
                        float4 wv = wr[c4];
                        float4 hv = *(const float4*)(hl + i * Di + c4 * 4);
                        acc += wv.x*hv.x + wv.y*hv.y + wv.z*hv.z + wv.w*hv.w;
                    }
                    xh[j] = acc;
                }
            }
            float cc;
            if (r == 0) cc = 1.0f;
            else {
                float lp = 0.f;
                #pragma unroll
                for (int j = 0; j < 16; ++j) lp += vs[j] * xh[j];
                if constexpr (LPO >= 2) lp += __shfl_xor(lp, 1, 64);
                if constexpr (LPO >= 4) lp += __shfl_xor(lp, 2, 64);
                float ev = act ? __expf(lp) : 0.f;
                float tot = ev;
                tot += __shfl_xor(tot,1,64); tot += __shfl_xor(tot,2,64);
                tot += __shfl_xor(tot,4,64); tot += __shfl_xor(tot,8,64);
                tot += __shfl_xor(tot,16,64); tot += __shfl_xor(tot,32,64);
                cc = ev * (float)LPO / tot;
            }
            #pragma unroll
            for (int j = 0; j < 16; ++j) sacc[j] += cc * xh[j];
        }
        if (r == 0) {
            #pragma unroll
            for (int j = 0; j < 16; ++j) sacc[j] *= (1.0f / O);
        }
        float n2 = 0.f;
        #pragma unroll
        for (int j = 0; j < 16; ++j) n2 += sacc[j] * sacc[j];
        if constexpr (LPO >= 2) n2 += __shfl_xor(n2, 1, 64);
        if constexpr (LPO >= 4) n2 += __shfl_xor(n2, 2, 64);
        float nrm = sqrtf(n2);
        float scale = n2 / ((1.f + n2) * (nrm + 1e-8f));
        if (r < 2) {
            #pragma unroll
            for (int j = 0; j < 16; ++j) vs[j] += scale * sacc[j];
        } else {
            if constexpr (FINAL) {
                float q = 0.f;
                #pragma unroll
                for (int j = 0; j < 16; ++j) { float vj = scale*sacc[j]; q += vj*vj; }
                if constexpr (LPO >= 2) q += __shfl_xor(q, 1, 64);
                if constexpr (LPO >= 4) q += __shfl_xor(q, 2, 64);
                if (act && (l % LPO) == 0) out[(size_t)e * O + o] = sqrtf(q);
            } else {
                __syncthreads();
                if (act) {
                    #pragma unroll
                    for (int j = 0; j < 16; ++j) hl[o * Do + d0 + j] = scale * sacc[j];
                }
                __syncthreads();
            }
        }
    }
}

__global__ __launch_bounds__(256) void fb_caps(const float* __restrict__ x,
                                               const float* __restrict__ W0,
                                               const float* __restrict__ W1,
                                               const float* __restrict__ W2,
                                               float* __restrict__ out) {
    __shared__ float hsh[4][1024];
    const int w = threadIdx.x >> 6;
    const int l = threadIdx.x & 63;
    const int e = blockIdx.x * 4 + w;
    float* hl = hsh[w];
    const float4* xr = (const float4*)(x + (size_t)e * 1024);
    float4* h4 = (float4*)hl;
    #pragma unroll
    for (int k = 0; k < 4; ++k) h4[l + 64 * k] = xr[l + 64 * k];
    __syncthreads();
    fb_layer<128, 8, 64, 16, false>(W0, hl, out, e, l);
    fb_layer<64, 16, 32, 32, false>(W1, hl, out, e, l);
    fb_layer<32, 32, 10, 64, true >(W2, hl, out, e, l);
}

extern "C" void kernel_launch(void* const* d_in, const int* in_sizes, int n_in,
                              void* d_out, int out_size, void* d_ws, size_t ws_size,
                              hipStream_t stream) {
    const float* x  = (const float*)d_in[0];   // [1024,1024]
    const float* W0 = (const float*)d_in[1];   // [64,128,16,8]
    const float* W1 = (const float*)d_in[2];   // [32,64,32,16]
    const float* W2 = (const float*)d_in[3];   // [10,32,64,32]
    float* out = (float*)d_out;                // [1024,10]

    const size_t DW0 = (size_t)64*128*16*8/2;   // u32 counts
    const size_t DW1 = (size_t)32*64*32*16/2;
    const size_t DW2 = (size_t)10*32*64*32/2;
    const size_t need = (DW0+DW1+DW2)*4;        // ~5.5 MB

    if (ws_size < need) {                       // safety net: proven slow path
        fb_caps<<<256, 256, 0, stream>>>(x, W0, W1, W2, out);
        return;
    }

    u32* Wb0 = (u32*)d_ws;
    u32* Wb1 = Wb0 + DW0;
    u32* Wb2 = Wb1 + DW1;

    k_conv<128, 8,64,16><<<512,256,0,stream>>>(W0, Wb0);
    k_conv< 64,16,32,32><<<512,256,0,stream>>>(W1, Wb1);
    k_conv< 32,32,10,64><<<512,256,0,stream>>>(W2, Wb2);

    caps_main<<<256, 512, 0, stream>>>(x, Wb0, Wb1, Wb2, out);
}